// Round 1
// baseline (258.543 us; speedup 1.0000x reference)
//
#include <hip/hip_runtime.h>
#include <hip/hip_bf16.h>
#include <stdint.h>

// Problem constants: B=4, N=M=2048, C=512, H=4, D_QK=256, D_V=128
#define SCALE_F 0.08838834764831845f  // 1/sqrt(128)

typedef __attribute__((ext_vector_type(8))) short short8;
typedef __attribute__((ext_vector_type(4))) float f32x4;

__device__ __forceinline__ void g2l16(const void* g, void* l) {
  __builtin_amdgcn_global_load_lds(
      (const __attribute__((address_space(1))) void*)g,
      (__attribute__((address_space(3))) void*)l, 16, 0, 0);
}

// ---------------- fp32 -> bf16 conversion (x, context, W_qkv, W_proj) --------
// x -> ab rows [0,8192); context -> ab rows [8192,16384); K=512 row-major.
__global__ __launch_bounds__(256) void convert_all(
    const float* __restrict__ x, const float* __restrict__ ctx,
    const float* __restrict__ wqkv, const float* __restrict__ wproj,
    __hip_bfloat16* __restrict__ ab, __hip_bfloat16* __restrict__ wb,
    __hip_bfloat16* __restrict__ wpb)
{
  size_t qi = (size_t)blockIdx.x * 256 + threadIdx.x;  // quad index
  const float* src; __hip_bfloat16* dst; size_t off;
  if (qi < 1048576)      { src = x;     dst = ab;           off = qi; }
  else if (qi < 2097152) { src = ctx;   dst = ab + 4194304; off = qi - 1048576; }
  else if (qi < 2228224) { src = wqkv;  dst = wb;           off = qi - 2097152; }
  else                   { src = wproj; dst = wpb;          off = qi - 2228224; }
  float4 v = ((const float4*)src)[off];
  union { __hip_bfloat16 h4[4]; uint2 u; } o;
  o.h4[0] = __float2bfloat16(v.x); o.h4[1] = __float2bfloat16(v.y);
  o.h4[2] = __float2bfloat16(v.z); o.h4[3] = __float2bfloat16(v.w);
  ((uint2*)dst)[off] = o.u;
}

// ---------------- V transpose: context (b,m,h*128+d) -> vt (bh, d, m) --------
__global__ __launch_bounds__(256) void transpose_v(
    const float* __restrict__ ctx, __hip_bfloat16* __restrict__ vt)
{
  __shared__ float tile[128][33];
  const int bid = blockIdx.x;          // B*H*64 = 1024
  const int mt = bid & 63;             // 32-row ctx tile
  const int bh = bid >> 6;             // b*4+h
  const int h = bh & 3, b = bh >> 2;
  const int tid = threadIdx.x;
  for (int i = 0; i < 16; ++i) {       // coalesced read along d
    int idx = i * 256 + tid;
    int mm = idx >> 7, d = idx & 127;
    tile[d][mm] = ctx[((size_t)b * 2048 + mt * 32 + mm) * 512 + h * 128 + d];
  }
  __syncthreads();
  for (int i = 0; i < 16; ++i) {       // coalesced write along m
    int idx = i * 256 + tid;
    int d = idx >> 5, mm = idx & 31;
    vt[((size_t)bh * 128 + d) * 2048 + mt * 32 + mm] = __float2bfloat16(tile[d][mm]);
  }
}

// ---------------- NT GEMM: C[r,o] = sum_k A[r,k]*B[o,k] -----------------------
// m97 pattern: 128x128 tile, BK=32, global_load_lds x16, 16x16x32 bf16 MFMA.
__global__ __launch_bounds__(256) void gemm_nt(
    const __hip_bfloat16* __restrict__ A, const __hip_bfloat16* __restrict__ B,
    float* __restrict__ C, int O, int K, int tiles_o)
{
  __shared__ __hip_bfloat16 sA[128 * 32];
  __shared__ __hip_bfloat16 sB[128 * 32];
  const int tid = threadIdx.x;
  const int wave = tid >> 6, lane = tid & 63;
  const int ln = lane & 15, q = lane >> 4;
  const int br = (blockIdx.x / tiles_o) * 128;
  const int bo = (blockIdx.x % tiles_o) * 128;
  const int wr = (wave >> 1) * 64, wc = (wave & 1) * 64;
  const __hip_bfloat16* Ab = A + (size_t)br * K;
  const __hip_bfloat16* Bb = B + (size_t)bo * K;
  const int row0 = tid >> 2, p0 = tid & 3;
  f32x4 acc[4][4] = {};
  for (int k0 = 0; k0 < K; k0 += 32) {
    for (int i = 0; i < 2; ++i) {
      int row = i * 64 + row0;
      g2l16(Ab + (size_t)row * K + k0 + p0 * 8, (char*)sA + (i * 256 + tid) * 16);
      g2l16(Bb + (size_t)row * K + k0 + p0 * 8, (char*)sB + (i * 256 + tid) * 16);
    }
    __syncthreads();
    short8 af[4], bfr[4];
    for (int mi = 0; mi < 4; ++mi)
      af[mi] = *(const short8*)(sA + (wr + mi * 16 + ln) * 32 + q * 8);
    for (int ni = 0; ni < 4; ++ni)
      bfr[ni] = *(const short8*)(sB + (wc + ni * 16 + ln) * 32 + q * 8);
    for (int mi = 0; mi < 4; ++mi)
      for (int ni = 0; ni < 4; ++ni)
        acc[mi][ni] = __builtin_amdgcn_mfma_f32_16x16x32_bf16(af[mi], bfr[ni], acc[mi][ni], 0, 0, 0);
    __syncthreads();
  }
  for (int mi = 0; mi < 4; ++mi)
    for (int ni = 0; ni < 4; ++ni) {
      int rg = br + wr + mi * 16 + q * 4;
      int cg = bo + wc + ni * 16 + ln;
      for (int r = 0; r < 4; ++r)
        C[(size_t)(rg + r) * O + cg] = acc[mi][ni][r];  // C/D: col=lane&15, row=q*4+r
    }
}

// ---------------- l2norm + radius/scale fold, fp32 -> bf16 -------------------
// proj rows [0,8192)=q, [8192,16384)=k; one wave per head chunk of 256.
// Fold r^2*SCALE into q so attention logits need no further scaling.
__global__ __launch_bounds__(256) void normalize_qk(
    const float* __restrict__ proj, const float* __restrict__ radius,
    __hip_bfloat16* __restrict__ qn, __hip_bfloat16* __restrict__ kn)
{
  const int r = blockIdx.x;
  const int h = threadIdx.x >> 6, lane = threadIdx.x & 63;
  float4 v = *(const float4*)(proj + (size_t)r * 1024 + h * 256 + lane * 4);
  float ss = v.x * v.x + v.y * v.y + v.z * v.z + v.w * v.w;
  for (int off = 1; off < 64; off <<= 1) ss += __shfl_xor(ss, off);
  float nrm = fmaxf(sqrtf(ss), 1e-12f);
  const bool isq = r < 8192;
  const int rr = isq ? r : r - 8192;
  const float rad = radius[h];
  const float sc = (isq ? rad * rad * SCALE_F : 1.0f) / nrm;
  __hip_bfloat16* dst = (isq ? qn : kn) +
      ((size_t)((rr >> 11) * 4 + h) * 2048 + (rr & 2047)) * 256 + lane * 4;
  union { __hip_bfloat16 h4[4]; uint2 u; } o;
  o.h4[0] = __float2bfloat16(v.x * sc);
  o.h4[1] = __float2bfloat16(v.y * sc);
  o.h4[2] = __float2bfloat16(v.z * sc);
  o.h4[3] = __float2bfloat16(v.w * sc);
  *(uint2*)dst = o.u;
}

// ---------------- flash attention (no max-tracking: |logit| <= sqrt(128)) ----
// grid = (B*H)*(N/64); block 256 (4 waves x 16 q-rows). BM=64 ctx tile.
__global__ __launch_bounds__(256) void attn(
    const __hip_bfloat16* __restrict__ qn,  // (bh, 2048, 256)
    const __hip_bfloat16* __restrict__ kn,  // (bh, 2048, 256)
    const __hip_bfloat16* __restrict__ vt,  // (bh, 128, 2048)
    __hip_bfloat16* __restrict__ ob)        // (b, n, h*128+d)
{
  __shared__ __hip_bfloat16 sK[8 * 64 * 32];   // 32KB, [kchunk][row][32]
  __shared__ __hip_bfloat16 sV[128 * 72];      // 18KB, Vt rows padded to 72
  __shared__ __hip_bfloat16 sP[4][16 * 72];    // 9KB, per-wave P, padded
  const int tid = threadIdx.x, wave = tid >> 6, lane = tid & 63;
  const int ln = lane & 15, q = lane >> 4;
  const int nt = blockIdx.x & 31, bh = blockIdx.x >> 5;
  const __hip_bfloat16* Q = qn + ((size_t)bh * 2048 + nt * 64 + wave * 16) * 256;
  const __hip_bfloat16* Kp = kn + (size_t)bh * 2048 * 256;
  const __hip_bfloat16* Vp = vt + (size_t)bh * 128 * 2048;
  short8 qf[8];                                // Q A-frags live in registers
  for (int kk = 0; kk < 8; ++kk)
    qf[kk] = *(const short8*)(Q + ln * 256 + kk * 32 + q * 8);
  f32x4 oacc[8] = {};
  float denom[4] = {0.f, 0.f, 0.f, 0.f};
  __hip_bfloat16* sPw = sP[wave];
  const int krow = tid >> 2, kp = tid & 3;
  for (int m0 = 0; m0 < 2048; m0 += 64) {
    // K tile: contiguous 32KB of kn, chunked so LDS row stride stays 64B
    for (int i = 0; i < 8; ++i)
      g2l16(Kp + (size_t)(m0 + krow) * 256 + i * 32 + kp * 8,
            (char*)sK + i * 4096 + tid * 16);
    // Vt tile (128 d-rows x 64 ctx), padded -> register staging
    for (int i = 0; i < 4; ++i) {
      int flat = i * 256 + tid;
      int d = flat >> 3, p = flat & 7;
      short8 t = *(const short8*)(Vp + (size_t)d * 2048 + m0 + p * 8);
      *(short8*)((char*)sV + d * 144 + p * 16) = t;
    }
    __syncthreads();
    // S = Q K^T (logits fully pre-scaled)
    f32x4 s[4];
    for (int ni = 0; ni < 4; ++ni) {
      f32x4 a = {};
      for (int kk = 0; kk < 8; ++kk) {
        short8 kf = *(const short8*)((char*)sK + kk * 4096 + (ni * 16 + ln) * 64 + q * 16);
        a = __builtin_amdgcn_mfma_f32_16x16x32_bf16(qf[kk], kf, a, 0, 0, 0);
      }
      s[ni] = a;
    }
    // exp + per-row partial sums; P -> LDS in A-layout-readable form
    float psum[4] = {0.f, 0.f, 0.f, 0.f};
    for (int ni = 0; ni < 4; ++ni)
      for (int r = 0; r < 4; ++r) {
        float e = __expf(s[ni][r]);
        psum[r] += e;
        sPw[(q * 4 + r) * 72 + ni * 16 + ln] = __float2bfloat16(e);
      }
    for (int off = 1; off < 16; off <<= 1)
      for (int r = 0; r < 4; ++r) psum[r] += __shfl_xor(psum[r], off);
    for (int r = 0; r < 4; ++r) denom[r] += psum[r];
    // cross-lane LDS dependency within the wave: drain ds_writes before reads
    asm volatile("s_waitcnt lgkmcnt(0)" ::: "memory");
    // O += P V
    for (int kc = 0; kc < 2; ++kc) {
      short8 pf = *(const short8*)((char*)sPw + ln * 144 + kc * 64 + q * 16);
      for (int vi = 0; vi < 8; ++vi) {
        short8 vf = *(const short8*)((char*)sV + (vi * 16 + ln) * 144 + kc * 64 + q * 16);
        oacc[vi] = __builtin_amdgcn_mfma_f32_16x16x32_bf16(pf, vf, oacc[vi], 0, 0, 0);
      }
    }
    __syncthreads();
  }
  const int b = bh >> 2, h = bh & 3;
  const int nrow = nt * 64 + wave * 16 + q * 4;
  for (int vi = 0; vi < 8; ++vi)
    for (int r = 0; r < 4; ++r) {
      float o = oacc[vi][r] / denom[r];
      ob[((size_t)b * 2048 + nrow + r) * 512 + h * 128 + vi * 16 + ln] = __float2bfloat16(o);
    }
}

// ---------------- launch ------------------------------------------------------
extern "C" void kernel_launch(void* const* d_in, const int* in_sizes, int n_in,
                              void* d_out, int out_size, void* d_ws, size_t ws_size,
                              hipStream_t stream) {
  const float* x      = (const float*)d_in[0];
  const float* ctx    = (const float*)d_in[1];
  const float* wqkv   = (const float*)d_in[2];
  const float* wproj  = (const float*)d_in[3];
  const float* radius = (const float*)d_in[4];
  char* ws = (char*)d_ws;
  // workspace layout (all 256B-aligned), total ~136 MB
  __hip_bfloat16* ab  = (__hip_bfloat16*)(ws);              // 16 MB (x+ctx bf16)
  __hip_bfloat16* wb  = (__hip_bfloat16*)(ws + 16777216);   // 1 MB
  __hip_bfloat16* wpb = (__hip_bfloat16*)(ws + 17825792);   // 0.5 MB
  float*          proj= (float*)(ws + 18350080);            // 64 MB
  __hip_bfloat16* qn  = (__hip_bfloat16*)(ws + 85458944);   // 16 MB
  __hip_bfloat16* kn  = (__hip_bfloat16*)(ws + 102236160);  // 16 MB
  __hip_bfloat16* vt  = (__hip_bfloat16*)(ws + 119013376);  // 8 MB
  __hip_bfloat16* ob  = (__hip_bfloat16*)(ws + 127401984);  // 8 MB
  float* out = (float*)d_out;

  convert_all<<<8960, 256, 0, stream>>>(x, ctx, wqkv, wproj, ab, wb, wpb);
  transpose_v<<<1024, 256, 0, stream>>>(ctx, vt);
  gemm_nt<<<1024, 256, 0, stream>>>(ab, wb, proj, 1024, 512, 8);     // 16384x1024
  normalize_qk<<<16384, 256, 0, stream>>>(proj, radius, qn, kn);
  attn<<<512, 256, 0, stream>>>(qn, kn, vt, ob);
  gemm_nt<<<256, 256, 0, stream>>>(ob, wpb, out, 512, 512, 4);       // 8192x512
}

// Round 2
// 253.341 us; speedup vs baseline: 1.0205x; 1.0205x over previous
//
#include <hip/hip_runtime.h>
#include <hip/hip_bf16.h>
#include <stdint.h>

// Problem constants: B=4, N=M=2048, C=512, H=4, D_QK=256, D_V=128
#define SCALE_F 0.08838834764831845f  // 1/sqrt(128)

typedef __attribute__((ext_vector_type(8))) short short8;
typedef __attribute__((ext_vector_type(4))) float f32x4;
typedef __attribute__((ext_vector_type(16))) float f32x16;

__device__ __forceinline__ void g2l16(const void* g, void* l) {
  __builtin_amdgcn_global_load_lds(
      (const __attribute__((address_space(1))) void*)g,
      (__attribute__((address_space(3))) void*)l, 16, 0, 0);
}

// ---------------- fp32 -> bf16 conversion (x, context, W_qkv, W_proj) --------
__global__ __launch_bounds__(256) void convert_all(
    const float* __restrict__ x, const float* __restrict__ ctx,
    const float* __restrict__ wqkv, const float* __restrict__ wproj,
    __hip_bfloat16* __restrict__ ab, __hip_bfloat16* __restrict__ wb,
    __hip_bfloat16* __restrict__ wpb)
{
  size_t qi = (size_t)blockIdx.x * 256 + threadIdx.x;  // quad index
  const float* src; __hip_bfloat16* dst; size_t off;
  if (qi < 1048576)      { src = x;     dst = ab;           off = qi; }
  else if (qi < 2097152) { src = ctx;   dst = ab + 4194304; off = qi - 1048576; }
  else if (qi < 2228224) { src = wqkv;  dst = wb;           off = qi - 2097152; }
  else                   { src = wproj; dst = wpb;          off = qi - 2228224; }
  float4 v = ((const float4*)src)[off];
  union { __hip_bfloat16 h4[4]; uint2 u; } o;
  o.h4[0] = __float2bfloat16(v.x); o.h4[1] = __float2bfloat16(v.y);
  o.h4[2] = __float2bfloat16(v.z); o.h4[3] = __float2bfloat16(v.w);
  ((uint2*)dst)[off] = o.u;
}

// ---------------- V transpose: context (b,m,h*128+d) -> vt (bh, d, m) --------
__global__ __launch_bounds__(256) void transpose_v(
    const float* __restrict__ ctx, __hip_bfloat16* __restrict__ vt)
{
  __shared__ float tile[128][33];
  const int bid = blockIdx.x;          // B*H*64 = 1024
  const int mt = bid & 63;             // 32-row ctx tile
  const int bh = bid >> 6;             // b*4+h
  const int h = bh & 3, b = bh >> 2;
  const int tid = threadIdx.x;
  for (int i = 0; i < 16; ++i) {       // coalesced read along d
    int idx = i * 256 + tid;
    int mm = idx >> 7, d = idx & 127;
    tile[d][mm] = ctx[((size_t)b * 2048 + mt * 32 + mm) * 512 + h * 128 + d];
  }
  __syncthreads();
  for (int i = 0; i < 16; ++i) {       // coalesced write along m
    int idx = i * 256 + tid;
    int d = idx >> 5, mm = idx & 31;
    vt[((size_t)bh * 128 + d) * 2048 + mt * 32 + mm] = __float2bfloat16(tile[d][mm]);
  }
}

// ---------------- NT GEMM: C[r,o] = sum_k A[r,k]*B[o,k] -----------------------
__global__ __launch_bounds__(256) void gemm_nt(
    const __hip_bfloat16* __restrict__ A, const __hip_bfloat16* __restrict__ B,
    float* __restrict__ C, int O, int K, int tiles_o)
{
  __shared__ __hip_bfloat16 sA[128 * 32];
  __shared__ __hip_bfloat16 sB[128 * 32];
  const int tid = threadIdx.x;
  const int wave = tid >> 6, lane = tid & 63;
  const int ln = lane & 15, q = lane >> 4;
  const int br = (blockIdx.x / tiles_o) * 128;
  const int bo = (blockIdx.x % tiles_o) * 128;
  const int wr = (wave >> 1) * 64, wc = (wave & 1) * 64;
  const __hip_bfloat16* Ab = A + (size_t)br * K;
  const __hip_bfloat16* Bb = B + (size_t)bo * K;
  const int row0 = tid >> 2, p0 = tid & 3;
  f32x4 acc[4][4] = {};
  for (int k0 = 0; k0 < K; k0 += 32) {
    for (int i = 0; i < 2; ++i) {
      int row = i * 64 + row0;
      g2l16(Ab + (size_t)row * K + k0 + p0 * 8, (char*)sA + (i * 256 + tid) * 16);
      g2l16(Bb + (size_t)row * K + k0 + p0 * 8, (char*)sB + (i * 256 + tid) * 16);
    }
    __syncthreads();
    short8 af[4], bfr[4];
    for (int mi = 0; mi < 4; ++mi)
      af[mi] = *(const short8*)(sA + (wr + mi * 16 + ln) * 32 + q * 8);
    for (int ni = 0; ni < 4; ++ni)
      bfr[ni] = *(const short8*)(sB + (wc + ni * 16 + ln) * 32 + q * 8);
    for (int mi = 0; mi < 4; ++mi)
      for (int ni = 0; ni < 4; ++ni)
        acc[mi][ni] = __builtin_amdgcn_mfma_f32_16x16x32_bf16(af[mi], bfr[ni], acc[mi][ni], 0, 0, 0);
    __syncthreads();
  }
  for (int mi = 0; mi < 4; ++mi)
    for (int ni = 0; ni < 4; ++ni) {
      int rg = br + wr + mi * 16 + q * 4;
      int cg = bo + wc + ni * 16 + ln;
      for (int r = 0; r < 4; ++r)
        C[(size_t)(rg + r) * O + cg] = acc[mi][ni][r];
    }
}

// ---------------- l2norm + radius/scale fold, fp32 -> bf16 -------------------
__global__ __launch_bounds__(256) void normalize_qk(
    const float* __restrict__ proj, const float* __restrict__ radius,
    __hip_bfloat16* __restrict__ qn, __hip_bfloat16* __restrict__ kn)
{
  const int r = blockIdx.x;
  const int h = threadIdx.x >> 6, lane = threadIdx.x & 63;
  float4 v = *(const float4*)(proj + (size_t)r * 1024 + h * 256 + lane * 4);
  float ss = v.x * v.x + v.y * v.y + v.z * v.z + v.w * v.w;
  for (int off = 1; off < 64; off <<= 1) ss += __shfl_xor(ss, off);
  float nrm = fmaxf(sqrtf(ss), 1e-12f);
  const bool isq = r < 8192;
  const int rr = isq ? r : r - 8192;
  const float rad = radius[h];
  const float sc = (isq ? rad * rad * SCALE_F : 1.0f) / nrm;
  __hip_bfloat16* dst = (isq ? qn : kn) +
      ((size_t)((rr >> 11) * 4 + h) * 2048 + (rr & 2047)) * 256 + lane * 4;
  union { __hip_bfloat16 h4[4]; uint2 u; } o;
  o.h4[0] = __float2bfloat16(v.x * sc);
  o.h4[1] = __float2bfloat16(v.y * sc);
  o.h4[2] = __float2bfloat16(v.z * sc);
  o.h4[3] = __float2bfloat16(v.w * sc);
  *(uint2*)dst = o.u;
}

// ---------------- flash attention v2 -----------------------------------------
// 32x32x16 MFMA, 32 q-rows/wave, XOR-swizzled LDS (conflict-free b128),
// double-buffered K/V tiles (BM=32), one barrier per iter.
// grid = (B*H)*(N/128) = 256 blocks; block 256 threads (4 waves x 32 q-rows).
__global__ __launch_bounds__(256, 1) void attn(
    const __hip_bfloat16* __restrict__ qn,  // (bh, 2048, 256)
    const __hip_bfloat16* __restrict__ kn,  // (bh, 2048, 256)
    const __hip_bfloat16* __restrict__ vt,  // (bh, 128, 2048)
    __hip_bfloat16* __restrict__ ob)        // (b, n, h*128+d)
{
  __shared__ __hip_bfloat16 sK[2][32 * 256];  // 16KB each; row=512B=32 chunks, swz c^=(row&7)
  __shared__ __hip_bfloat16 sV[2][128 * 32];  // 8KB each; row=64B=4 chunks, swz c^=((row>>1)&3)
  __shared__ __hip_bfloat16 sP[4][32 * 40];   // 2.5KB/wave, rows padded to 40 elems (80B)
  const int tid = threadIdx.x, wave = tid >> 6, lane = tid & 63;
  const int m32 = lane & 31, hi = lane >> 5;
  const int nt = blockIdx.x & 15, bh = blockIdx.x >> 4;
  const __hip_bfloat16* Q = qn + ((size_t)bh * 2048 + nt * 128 + wave * 32) * 256;
  const __hip_bfloat16* Kp = kn + (size_t)bh * 2048 * 256;
  const __hip_bfloat16* Vp = vt + (size_t)bh * 128 * 2048;

  // Q A-frags in registers: A[m=lane&31][k=(lane>>5)*8+j], 16 k-chunks of 16
  short8 qf[16];
  for (int kk = 0; kk < 16; ++kk)
    qf[kk] = *(const short8*)(Q + m32 * 256 + kk * 16 + hi * 8);

  f32x16 oacc[4];
  float denom[16];
  for (int i = 0; i < 4; ++i)
    for (int j = 0; j < 16; ++j) oacc[i][j] = 0.f;
  for (int j = 0; j < 16; ++j) denom[j] = 0.f;
  __hip_bfloat16* sPw = sP[wave];

  // stage tile 0 into buffer 0
  for (int i = 0; i < 4; ++i) {
    int D = i * 256 + tid, row = D >> 5, cc = D & 31;
    g2l16(Kp + (size_t)row * 256 + ((cc ^ (row & 7)) << 3), (char*)sK[0] + D * 16);
  }
  for (int i = 0; i < 2; ++i) {
    int D = i * 256 + tid, rd = D >> 2, cc = D & 3;
    g2l16(Vp + (size_t)rd * 2048 + ((cc ^ ((rd >> 1) & 3)) << 3), (char*)sV[0] + D * 16);
  }
  __syncthreads();

  for (int it = 0; it < 64; ++it) {
    const int cur = it & 1, nxt = cur ^ 1;
    // prefetch next tile (drained by the barrier at iter end, ~full shadow)
    if (it + 1 < 64) {
      const int m1 = (it + 1) * 32;
      for (int i = 0; i < 4; ++i) {
        int D = i * 256 + tid, row = D >> 5, cc = D & 31;
        g2l16(Kp + (size_t)(m1 + row) * 256 + ((cc ^ (row & 7)) << 3),
              (char*)sK[nxt] + D * 16);
      }
      for (int i = 0; i < 2; ++i) {
        int D = i * 256 + tid, rd = D >> 2, cc = D & 3;
        g2l16(Vp + (size_t)rd * 2048 + m1 + ((cc ^ ((rd >> 1) & 3)) << 3),
              (char*)sV[nxt] + D * 16);
      }
    }
    // S = Q K^T for this 32-ctx tile (logits fully pre-scaled; |S| <= 11.32)
    const __hip_bfloat16* sKc = sK[cur];
    f32x16 s;
    for (int j = 0; j < 16; ++j) s[j] = 0.f;
    for (int kk = 0; kk < 16; ++kk) {
      int c = kk * 2 + hi;
      short8 kf = *(const short8*)(sKc + m32 * 256 + ((c ^ (m32 & 7)) << 3));
      s = __builtin_amdgcn_mfma_f32_32x32x16_bf16(qf[kk], kf, s, 0, 0, 0);
    }
    // exp, accumulate denom, P -> LDS [q][ctx] (pad 40)
    for (int reg = 0; reg < 16; ++reg) {
      float e = __expf(s[reg]);
      denom[reg] += e;
      int row = (reg & 3) + 8 * (reg >> 2) + 4 * hi;
      sPw[row * 40 + m32] = __float2bfloat16(e);
    }
    asm volatile("s_waitcnt lgkmcnt(0)" ::: "memory");  // wave-local P visibility
    // O += P V
    const __hip_bfloat16* sVc = sV[cur];
    for (int kc = 0; kc < 2; ++kc) {
      short8 pf = *(const short8*)(sPw + m32 * 40 + kc * 16 + hi * 8);
      for (int vi = 0; vi < 4; ++vi) {
        int rd = vi * 32 + m32;
        int c = kc * 2 + hi;
        short8 vf = *(const short8*)(sVc + rd * 32 + ((c ^ ((rd >> 1) & 3)) << 3));
        oacc[vi] = __builtin_amdgcn_mfma_f32_32x32x16_bf16(pf, vf, oacc[vi], 0, 0, 0);
      }
    }
    __syncthreads();  // drains prefetch vmcnt + guards buffer swap
  }

  // reduce denom across the 32 ctx-col lanes (each half holds its own rows)
  for (int reg = 0; reg < 16; ++reg)
    for (int off = 1; off < 32; off <<= 1)
      denom[reg] += __shfl_xor(denom[reg], off);

  const int b = bh >> 2, h = bh & 3;
  for (int vi = 0; vi < 4; ++vi)
    for (int reg = 0; reg < 16; ++reg) {
      int row = nt * 128 + wave * 32 + (reg & 3) + 8 * (reg >> 2) + 4 * hi;
      float o = oacc[vi][reg] / denom[reg];
      ob[((size_t)b * 2048 + row) * 512 + h * 128 + vi * 32 + m32] = __float2bfloat16(o);
    }
}

// ---------------- launch ------------------------------------------------------
extern "C" void kernel_launch(void* const* d_in, const int* in_sizes, int n_in,
                              void* d_out, int out_size, void* d_ws, size_t ws_size,
                              hipStream_t stream) {
  const float* x      = (const float*)d_in[0];
  const float* ctx    = (const float*)d_in[1];
  const float* wqkv   = (const float*)d_in[2];
  const float* wproj  = (const float*)d_in[3];
  const float* radius = (const float*)d_in[4];
  char* ws = (char*)d_ws;
  __hip_bfloat16* ab  = (__hip_bfloat16*)(ws);              // 16 MB (x+ctx bf16)
  __hip_bfloat16* wb  = (__hip_bfloat16*)(ws + 16777216);   // 1 MB
  __hip_bfloat16* wpb = (__hip_bfloat16*)(ws + 17825792);   // 0.5 MB
  float*          proj= (float*)(ws + 18350080);            // 64 MB
  __hip_bfloat16* qn  = (__hip_bfloat16*)(ws + 85458944);   // 16 MB
  __hip_bfloat16* kn  = (__hip_bfloat16*)(ws + 102236160);  // 16 MB
  __hip_bfloat16* vt  = (__hip_bfloat16*)(ws + 119013376);  // 8 MB
  __hip_bfloat16* ob  = (__hip_bfloat16*)(ws + 127401984);  // 8 MB
  float* out = (float*)d_out;

  convert_all<<<8960, 256, 0, stream>>>(x, ctx, wqkv, wproj, ab, wb, wpb);
  transpose_v<<<1024, 256, 0, stream>>>(ctx, vt);
  gemm_nt<<<1024, 256, 0, stream>>>(ab, wb, proj, 1024, 512, 8);     // 16384x1024
  normalize_qk<<<16384, 256, 0, stream>>>(proj, radius, qn, kn);
  attn<<<256, 256, 0, stream>>>(qn, kn, vt, ob);
  gemm_nt<<<256, 256, 0, stream>>>(ob, wpb, out, 512, 512, 4);       // 8192x512
}

// Round 3
// 227.155 us; speedup vs baseline: 1.1382x; 1.1153x over previous
//
#include <hip/hip_runtime.h>
#include <hip/hip_bf16.h>
#include <stdint.h>

// Problem constants: B=4, N=M=2048, C=512, H=4, D_QK=256, D_V=128
#define SCALE_F 0.08838834764831845f  // 1/sqrt(128)

typedef __attribute__((ext_vector_type(8))) short short8;
typedef __attribute__((ext_vector_type(4))) float f32x4;
typedef __attribute__((ext_vector_type(16))) float f32x16;

__device__ __forceinline__ void g2l16(const void* g, void* l) {
  __builtin_amdgcn_global_load_lds(
      (const __attribute__((address_space(1))) void*)g,
      (__attribute__((address_space(3))) void*)l, 16, 0, 0);
}

// ---------------- fp32 -> bf16 conversion (x, context, W_qkv, W_proj) --------
__global__ __launch_bounds__(256) void convert_all(
    const float* __restrict__ x, const float* __restrict__ ctx,
    const float* __restrict__ wqkv, const float* __restrict__ wproj,
    __hip_bfloat16* __restrict__ ab, __hip_bfloat16* __restrict__ wb,
    __hip_bfloat16* __restrict__ wpb)
{
  size_t qi = (size_t)blockIdx.x * 256 + threadIdx.x;  // quad index
  const float* src; __hip_bfloat16* dst; size_t off;
  if (qi < 1048576)      { src = x;     dst = ab;           off = qi; }
  else if (qi < 2097152) { src = ctx;   dst = ab + 4194304; off = qi - 1048576; }
  else if (qi < 2228224) { src = wqkv;  dst = wb;           off = qi - 2097152; }
  else                   { src = wproj; dst = wpb;          off = qi - 2228224; }
  float4 v = ((const float4*)src)[off];
  union { __hip_bfloat16 h4[4]; uint2 u; } o;
  o.h4[0] = __float2bfloat16(v.x); o.h4[1] = __float2bfloat16(v.y);
  o.h4[2] = __float2bfloat16(v.z); o.h4[3] = __float2bfloat16(v.w);
  ((uint2*)dst)[off] = o.u;
}

// ---------------- V transpose: context (b,m,h*128+d) -> vt (bh, d, m) --------
__global__ __launch_bounds__(256) void transpose_v(
    const float* __restrict__ ctx, __hip_bfloat16* __restrict__ vt)
{
  __shared__ float tile[128][33];
  const int bid = blockIdx.x;          // B*H*64 = 1024
  const int mt = bid & 63;             // 32-row ctx tile
  const int bh = bid >> 6;             // b*4+h
  const int h = bh & 3, b = bh >> 2;
  const int tid = threadIdx.x;
  for (int i = 0; i < 16; ++i) {       // coalesced read along d
    int idx = i * 256 + tid;
    int mm = idx >> 7, d = idx & 127;
    tile[d][mm] = ctx[((size_t)b * 2048 + mt * 32 + mm) * 512 + h * 128 + d];
  }
  __syncthreads();
  for (int i = 0; i < 16; ++i) {       // coalesced write along m
    int idx = i * 256 + tid;
    int d = idx >> 5, mm = idx & 31;
    vt[((size_t)bh * 128 + d) * 2048 + mt * 32 + mm] = __float2bfloat16(tile[d][mm]);
  }
}

// ---------------- NT GEMM: C[r,o] = sum_k A[r,k]*B[o,k] -----------------------
__global__ __launch_bounds__(256) void gemm_nt(
    const __hip_bfloat16* __restrict__ A, const __hip_bfloat16* __restrict__ B,
    float* __restrict__ C, int O, int K, int tiles_o)
{
  __shared__ __hip_bfloat16 sA[128 * 32];
  __shared__ __hip_bfloat16 sB[128 * 32];
  const int tid = threadIdx.x;
  const int wave = tid >> 6, lane = tid & 63;
  const int ln = lane & 15, q = lane >> 4;
  const int br = (blockIdx.x / tiles_o) * 128;
  const int bo = (blockIdx.x % tiles_o) * 128;
  const int wr = (wave >> 1) * 64, wc = (wave & 1) * 64;
  const __hip_bfloat16* Ab = A + (size_t)br * K;
  const __hip_bfloat16* Bb = B + (size_t)bo * K;
  const int row0 = tid >> 2, p0 = tid & 3;
  f32x4 acc[4][4] = {};
  for (int k0 = 0; k0 < K; k0 += 32) {
    for (int i = 0; i < 2; ++i) {
      int row = i * 64 + row0;
      g2l16(Ab + (size_t)row * K + k0 + p0 * 8, (char*)sA + (i * 256 + tid) * 16);
      g2l16(Bb + (size_t)row * K + k0 + p0 * 8, (char*)sB + (i * 256 + tid) * 16);
    }
    __syncthreads();
    short8 af[4], bfr[4];
    for (int mi = 0; mi < 4; ++mi)
      af[mi] = *(const short8*)(sA + (wr + mi * 16 + ln) * 32 + q * 8);
    for (int ni = 0; ni < 4; ++ni)
      bfr[ni] = *(const short8*)(sB + (wc + ni * 16 + ln) * 32 + q * 8);
    for (int mi = 0; mi < 4; ++mi)
      for (int ni = 0; ni < 4; ++ni)
        acc[mi][ni] = __builtin_amdgcn_mfma_f32_16x16x32_bf16(af[mi], bfr[ni], acc[mi][ni], 0, 0, 0);
    __syncthreads();
  }
  for (int mi = 0; mi < 4; ++mi)
    for (int ni = 0; ni < 4; ++ni) {
      int rg = br + wr + mi * 16 + q * 4;
      int cg = bo + wc + ni * 16 + ln;
      for (int r = 0; r < 4; ++r)
        C[(size_t)(rg + r) * O + cg] = acc[mi][ni][r];
    }
}

// ---------------- l2norm + radius/scale fold, fp32 -> bf16 -------------------
__global__ __launch_bounds__(256) void normalize_qk(
    const float* __restrict__ proj, const float* __restrict__ radius,
    __hip_bfloat16* __restrict__ qn, __hip_bfloat16* __restrict__ kn)
{
  const int r = blockIdx.x;
  const int h = threadIdx.x >> 6, lane = threadIdx.x & 63;
  float4 v = *(const float4*)(proj + (size_t)r * 1024 + h * 256 + lane * 4);
  float ss = v.x * v.x + v.y * v.y + v.z * v.z + v.w * v.w;
  for (int off = 1; off < 64; off <<= 1) ss += __shfl_xor(ss, off);
  float nrm = fmaxf(sqrtf(ss), 1e-12f);
  const bool isq = r < 8192;
  const int rr = isq ? r : r - 8192;
  const float rad = radius[h];
  const float sc = (isq ? rad * rad * SCALE_F : 1.0f) / nrm;
  __hip_bfloat16* dst = (isq ? qn : kn) +
      ((size_t)((rr >> 11) * 4 + h) * 2048 + (rr & 2047)) * 256 + lane * 4;
  union { __hip_bfloat16 h4[4]; uint2 u; } o;
  o.h4[0] = __float2bfloat16(v.x * sc);
  o.h4[1] = __float2bfloat16(v.y * sc);
  o.h4[2] = __float2bfloat16(v.z * sc);
  o.h4[3] = __float2bfloat16(v.w * sc);
  *(uint2*)dst = o.u;
}

// ---------------- flash attention v3: ctx-split for occupancy ----------------
// 32x32x16 MFMA, 32 q-rows/wave, XOR-swizzled LDS, double-buffered K/V (BM=32).
// grid = 512: bh(16) x nt(16) x half(2), swizzled so same-bh -> same XCD.
// Writes UNNORMALIZED partial O (fp32) + partial denom; combine() merges.
__global__ __launch_bounds__(256, 2) void attn(
    const __hip_bfloat16* __restrict__ qn,  // (bh, 2048, 256)
    const __hip_bfloat16* __restrict__ kn,  // (bh, 2048, 256)
    const __hip_bfloat16* __restrict__ vt,  // (bh, 128, 2048)
    float* __restrict__ Op,                 // (half, bh, 2048, 128) fp32
    float* __restrict__ den)                // (half, bh, 2048) fp32
{
  __shared__ __hip_bfloat16 sK[2][32 * 256];  // 16KB each; swz c^=(row&7)
  __shared__ __hip_bfloat16 sV[2][128 * 32];  // 8KB each; swz c^=((row>>1)&3)
  __shared__ __hip_bfloat16 sP[4][32 * 40];   // rows padded to 40 elems
  const int tid = threadIdx.x, wave = tid >> 6, lane = tid & 63;
  const int m32 = lane & 31, hi = lane >> 5;
  // XCD-aware decode: bh constant per XCD (round-robin blockIdx % 8)
  const int i = blockIdx.x;
  const int bh = (i & 7) + 8 * ((i >> 3) & 1);
  const int half = (i >> 4) & 1;
  const int nt = i >> 5;                      // [0,16)
  const int mbase = half * 1024;
  const __hip_bfloat16* Q = qn + ((size_t)bh * 2048 + nt * 128 + wave * 32) * 256;
  const __hip_bfloat16* Kp = kn + (size_t)bh * 2048 * 256;
  const __hip_bfloat16* Vp = vt + (size_t)bh * 128 * 2048;

  // Q A-frags in registers: A[m=lane&31][k=(lane>>5)*8+j], 16 k-chunks of 16
  short8 qf[16];
  for (int kk = 0; kk < 16; ++kk)
    qf[kk] = *(const short8*)(Q + m32 * 256 + kk * 16 + hi * 8);

  f32x16 oacc[4];
  float denom[16];
  for (int v = 0; v < 4; ++v)
    for (int j = 0; j < 16; ++j) oacc[v][j] = 0.f;
  for (int j = 0; j < 16; ++j) denom[j] = 0.f;
  __hip_bfloat16* sPw = sP[wave];

  // stage tile 0 into buffer 0
  for (int t = 0; t < 4; ++t) {
    int D = t * 256 + tid, row = D >> 5, cc = D & 31;
    g2l16(Kp + (size_t)(mbase + row) * 256 + ((cc ^ (row & 7)) << 3),
          (char*)sK[0] + D * 16);
  }
  for (int t = 0; t < 2; ++t) {
    int D = t * 256 + tid, rd = D >> 2, cc = D & 3;
    g2l16(Vp + (size_t)rd * 2048 + mbase + ((cc ^ ((rd >> 1) & 3)) << 3),
          (char*)sV[0] + D * 16);
  }
  __syncthreads();

  for (int it = 0; it < 32; ++it) {
    const int cur = it & 1, nxt = cur ^ 1;
    if (it + 1 < 32) {
      const int m1 = mbase + (it + 1) * 32;
      for (int t = 0; t < 4; ++t) {
        int D = t * 256 + tid, row = D >> 5, cc = D & 31;
        g2l16(Kp + (size_t)(m1 + row) * 256 + ((cc ^ (row & 7)) << 3),
              (char*)sK[nxt] + D * 16);
      }
      for (int t = 0; t < 2; ++t) {
        int D = t * 256 + tid, rd = D >> 2, cc = D & 3;
        g2l16(Vp + (size_t)rd * 2048 + m1 + ((cc ^ ((rd >> 1) & 3)) << 3),
              (char*)sV[nxt] + D * 16);
      }
    }
    // S = Q K^T, two independent 8-deep MFMA chains for ILP
    const __hip_bfloat16* sKc = sK[cur];
    f32x16 sa, sb;
    for (int j = 0; j < 16; ++j) { sa[j] = 0.f; sb[j] = 0.f; }
    for (int kk = 0; kk < 8; ++kk) {
      int ca = kk * 2 + hi, cb = (kk + 8) * 2 + hi;
      short8 kfa = *(const short8*)(sKc + m32 * 256 + ((ca ^ (m32 & 7)) << 3));
      short8 kfb = *(const short8*)(sKc + m32 * 256 + ((cb ^ (m32 & 7)) << 3));
      sa = __builtin_amdgcn_mfma_f32_32x32x16_bf16(qf[kk], kfa, sa, 0, 0, 0);
      sb = __builtin_amdgcn_mfma_f32_32x32x16_bf16(qf[kk + 8], kfb, sb, 0, 0, 0);
    }
    // exp, accumulate denom, P -> LDS [q][ctx] (pad 40)
    for (int reg = 0; reg < 16; ++reg) {
      float e = __expf(sa[reg] + sb[reg]);
      denom[reg] += e;
      int row = (reg & 3) + 8 * (reg >> 2) + 4 * hi;
      sPw[row * 40 + m32] = __float2bfloat16(e);
    }
    asm volatile("s_waitcnt lgkmcnt(0)" ::: "memory");  // wave-local P visibility
    // O += P V
    const __hip_bfloat16* sVc = sV[cur];
    for (int kc = 0; kc < 2; ++kc) {
      short8 pf = *(const short8*)(sPw + m32 * 40 + kc * 16 + hi * 8);
      for (int vi = 0; vi < 4; ++vi) {
        int rd = vi * 32 + m32;
        int c = kc * 2 + hi;
        short8 vf = *(const short8*)(sVc + rd * 32 + ((c ^ ((rd >> 1) & 3)) << 3));
        oacc[vi] = __builtin_amdgcn_mfma_f32_32x32x16_bf16(pf, vf, oacc[vi], 0, 0, 0);
      }
    }
    __syncthreads();  // drains prefetch vmcnt + guards buffer swap
  }

  // partial denom: reduce across the 32 ctx lanes of each half-wave
  for (int reg = 0; reg < 16; ++reg)
    for (int off = 1; off < 32; off <<= 1)
      denom[reg] += __shfl_xor(denom[reg], off);

  float* Opb = Op + ((size_t)(half * 16 + bh) * 2048) * 128;
  float* denb = den + (size_t)(half * 16 + bh) * 2048;
  const int rbase = nt * 128 + wave * 32;
  for (int vi = 0; vi < 4; ++vi)
    for (int reg = 0; reg < 16; ++reg) {
      int row = rbase + (reg & 3) + 8 * (reg >> 2) + 4 * hi;
      Opb[(size_t)row * 128 + vi * 32 + m32] = oacc[vi][reg];
    }
  if (m32 == 0)
    for (int reg = 0; reg < 16; ++reg)
      denb[rbase + (reg & 3) + 8 * (reg >> 2) + 4 * hi] = denom[reg];
}

// ---------------- combine ctx halves -> bf16 ob ------------------------------
__global__ __launch_bounds__(256) void combine(
    const float* __restrict__ Op, const float* __restrict__ den,
    __hip_bfloat16* __restrict__ ob)
{
  int qi = blockIdx.x * 256 + threadIdx.x;   // 1,048,576 float4-quads
  int r = qi >> 5, dq = qi & 5 * 6 + 1;      // r=row, dq in [0,32)
  dq = qi & 31;
  int bh = r >> 11, n = r & 2047, b = bh >> 2, h = bh & 3;
  float4 o0 = ((const float4*)Op)[qi];
  float4 o1 = ((const float4*)(Op + 4194304))[qi];
  float inv = 1.0f / (den[r] + den[32768 + r]);
  union { __hip_bfloat16 h4[4]; uint2 u; } o;
  o.h4[0] = __float2bfloat16((o0.x + o1.x) * inv);
  o.h4[1] = __float2bfloat16((o0.y + o1.y) * inv);
  o.h4[2] = __float2bfloat16((o0.z + o1.z) * inv);
  o.h4[3] = __float2bfloat16((o0.w + o1.w) * inv);
  *(uint2*)&ob[((size_t)b * 2048 + n) * 512 + h * 128 + dq * 4] = o.u;
}

// ---------------- launch ------------------------------------------------------
extern "C" void kernel_launch(void* const* d_in, const int* in_sizes, int n_in,
                              void* d_out, int out_size, void* d_ws, size_t ws_size,
                              hipStream_t stream) {
  const float* x      = (const float*)d_in[0];
  const float* ctx    = (const float*)d_in[1];
  const float* wqkv   = (const float*)d_in[2];
  const float* wproj  = (const float*)d_in[3];
  const float* radius = (const float*)d_in[4];
  char* ws = (char*)d_ws;
  __hip_bfloat16* ab  = (__hip_bfloat16*)(ws);              // 16 MB (x+ctx bf16)
  __hip_bfloat16* wb  = (__hip_bfloat16*)(ws + 16777216);   // 1 MB
  __hip_bfloat16* wpb = (__hip_bfloat16*)(ws + 17825792);   // 0.5 MB
  float*          proj= (float*)(ws + 18350080);            // 64 MB (dead after normalize)
  float*          Op  = proj;                               // 33.5 MB partial O (reuse)
  float*          den = (float*)(ws + 18350080 + 33554432); // 256 KB partial denom
  __hip_bfloat16* qn  = (__hip_bfloat16*)(ws + 85458944);   // 16 MB
  __hip_bfloat16* kn  = (__hip_bfloat16*)(ws + 102236160);  // 16 MB
  __hip_bfloat16* vt  = (__hip_bfloat16*)(ws + 119013376);  // 8 MB
  __hip_bfloat16* ob  = (__hip_bfloat16*)(ws + 127401984);  // 8 MB
  float* out = (float*)d_out;

  convert_all<<<8960, 256, 0, stream>>>(x, ctx, wqkv, wproj, ab, wb, wpb);
  transpose_v<<<1024, 256, 0, stream>>>(ctx, vt);
  gemm_nt<<<1024, 256, 0, stream>>>(ab, wb, proj, 1024, 512, 8);     // 16384x1024
  normalize_qk<<<16384, 256, 0, stream>>>(proj, radius, qn, kn);
  attn<<<512, 256, 0, stream>>>(qn, kn, vt, Op, den);
  combine<<<4096, 256, 0, stream>>>(Op, den, ob);
  gemm_nt<<<256, 256, 0, stream>>>(ob, wpb, out, 512, 512, 4);       // 8192x512
}